// Round 9
// baseline (294.446 us; speedup 1.0000x reference)
//
#include <hip/hip_runtime.h>
#include <hip/hip_bf16.h>

#define HD 128   // hidden/feature dim
#define NL 7     // label dim
#define BCAP 6144  // per-bucket stage capacity (avg 4082 for E=800K/196 buckets; +50% headroom)

__device__ __forceinline__ unsigned short f2bf(float f) {
    __hip_bfloat16 b = __float2bfloat16(f);   // RNE
    return *reinterpret_cast<unsigned short*>(&b);
}
__device__ __forceinline__ float bf2f(unsigned short u) {
    unsigned int x = ((unsigned int)u) << 16;
    return __uint_as_float(x);
}

// ---------------- workspace zeroing ----------------

__global__ __launch_bounds__(256) void k_zero(int* __restrict__ gbcur, int nb,
                                              float* __restrict__ sums, int m) {
    int i = blockIdx.x * 256 + threadIdx.x;
    if (i < nb) gbcur[i] = 0;
    if (i < m) sums[i] = 0.f;
}

// ---------------- CSR build via bucketed counting sort ----------------

__global__ __launch_bounds__(256) void k_bucket(const int* __restrict__ src,
                                                const int* __restrict__ dst, int E,
                                                int* __restrict__ gbcur,
                                                int* __restrict__ stage, int nb) {
    __shared__ int lh[256];
    __shared__ int gb[256];
    int t = threadIdx.x;
    if (t < nb) lh[t] = 0;
    __syncthreads();

    int e0 = blockIdx.x * 4096;
    int bk[16]; int lr[16]; int rec[16];
    #pragma unroll
    for (int j = 0; j < 16; ++j) {
        int e = e0 + j * 256 + t;
        if (e < E) {
            int d = dst[e];
            int s = src[e];
            bk[j]  = d >> 8;
            rec[j] = ((d & 255) << 16) | s;       // src < 65536
            lr[j]  = atomicAdd(&lh[bk[j]], 1);    // local rank
        } else {
            bk[j] = -1; lr[j] = 0; rec[j] = 0;
        }
    }
    __syncthreads();
    if (t < nb) gb[t] = atomicAdd(&gbcur[t], lh[t]);   // reserve run per bucket
    __syncthreads();
    #pragma unroll
    for (int j = 0; j < 16; ++j) {
        if (bk[j] >= 0) {
            int p = gb[bk[j]] + lr[j];
            if (p < BCAP) stage[bk[j] * BCAP + p] = rec[j];
        }
    }
}

__global__ __launch_bounds__(256) void k_bscan(const int* __restrict__ gbcnt,
                                               int* __restrict__ bbase, int nb,
                                               int* __restrict__ row_start, int n) {
    __shared__ int s[256];
    int t = threadIdx.x;
    int val = (t < nb) ? gbcnt[t] : 0;
    s[t] = val;
    __syncthreads();
    #pragma unroll
    for (int off = 1; off < 256; off <<= 1) {
        int v = (t >= off) ? s[t - off] : 0;
        __syncthreads();
        s[t] += v;
        __syncthreads();
    }
    if (t < nb) bbase[t] = s[t] - val;
    if (t == 255) { bbase[nb] = s[255]; row_start[n] = s[255]; }
}

__global__ __launch_bounds__(256) void k_build(const int* __restrict__ stage,
                                               const int* __restrict__ gbcnt,
                                               const int* __restrict__ bbase,
                                               int* __restrict__ col,
                                               int* __restrict__ row_start,
                                               float* __restrict__ dinv, int n) {
    __shared__ int rec_s[BCAP];
    __shared__ unsigned short rank_s[BCAP];
    __shared__ int hist[256];
    __shared__ int scan_s[256];
    int b = blockIdx.x, t = threadIdx.x;
    int cnt  = min(gbcnt[b], BCAP);
    int base = bbase[b];
    int node0 = b << 8;

    hist[t] = 0;
    __syncthreads();
    for (int e = t; e < cnt; e += 256) {
        int r = stage[b * BCAP + e];
        rec_s[e] = r;
        rank_s[e] = (unsigned short)atomicAdd(&hist[r >> 16], 1);
    }
    __syncthreads();

    int deg = hist[t];
    int node = node0 + t;
    if (node < n) dinv[node] = 1.0f / sqrtf((float)(deg + 1));  // +1 self loop

    scan_s[t] = deg;
    __syncthreads();
    #pragma unroll
    for (int off = 1; off < 256; off <<= 1) {
        int v = (t >= off) ? scan_s[t - off] : 0;
        __syncthreads();
        scan_s[t] += v;
        __syncthreads();
    }
    int lrs = scan_s[t] - deg;      // local exclusive prefix
    hist[t] = lrs;                  // reuse hist as lrs table
    if (node < n) row_start[node] = base + lrs;
    __syncthreads();

    for (int e = t; e < cnt; e += 256) {
        int r = rec_s[e];
        col[base + hist[r >> 16] + rank_s[e]] = r & 0xFFFF;
    }
}

// ---------------- per-edge weight precompute: ecol[e] = {src, dinv[src]*dinv[dst]} ----------

__global__ __launch_bounds__(256) void k_wnorm(const int* __restrict__ col,
                                               const int* __restrict__ row_start,
                                               const float* __restrict__ dinv,
                                               int2* __restrict__ ecol, int n) {
    int tid = blockIdx.x * 256 + threadIdx.x;
    int node = tid >> 4;
    int l = tid & 15;
    if (node >= n) return;
    float dv = dinv[node];
    int e1 = row_start[node + 1];
    for (int e = row_start[node] + l; e < e1; e += 16) {
        int s = col[e];
        int2 p;
        p.x = s;
        p.y = __float_as_int(dinv[s] * dv);
        ecol[e] = p;
    }
}

// ---------------- GEMM: Y[n,128](bf16) = X[n,128](f32) @ W[128,128](f32) ----------------

__global__ __launch_bounds__(256) void k_gemm128(const float* __restrict__ X,
                                                 const float* __restrict__ W,
                                                 unsigned short* __restrict__ Y, int n) {
    __shared__ float xs[64][HD];
    int tid = threadIdx.x;
    int row0 = blockIdx.x * 64;

    #pragma unroll
    for (int j = 0; j < 8; ++j) {
        int f4 = tid + j * 256;        // 0..2047
        int r = f4 >> 5;               // 32 float4 per row
        int c = (f4 & 31) * 4;
        int gr = row0 + r;
        float4 v = make_float4(0.f, 0.f, 0.f, 0.f);
        if (gr < n) v = *(const float4*)&X[(size_t)gr * HD + c];
        *(float4*)&xs[r][c] = v;
    }
    __syncthreads();

    int cg = (tid & 31) * 4;
    int rg = (tid >> 5) * 8;

    float4 acc[8];
    #pragma unroll
    for (int i = 0; i < 8; ++i) acc[i] = make_float4(0.f, 0.f, 0.f, 0.f);

    for (int k = 0; k < HD; k += 4) {
        float4 w0 = *(const float4*)&W[(size_t)(k + 0) * HD + cg];
        float4 w1 = *(const float4*)&W[(size_t)(k + 1) * HD + cg];
        float4 w2 = *(const float4*)&W[(size_t)(k + 2) * HD + cg];
        float4 w3 = *(const float4*)&W[(size_t)(k + 3) * HD + cg];
        #pragma unroll
        for (int i = 0; i < 8; ++i) {
            float4 xv = *(const float4*)&xs[rg + i][k];
            acc[i].x = fmaf(xv.x, w0.x, acc[i].x);
            acc[i].y = fmaf(xv.x, w0.y, acc[i].y);
            acc[i].z = fmaf(xv.x, w0.z, acc[i].z);
            acc[i].w = fmaf(xv.x, w0.w, acc[i].w);
            acc[i].x = fmaf(xv.y, w1.x, acc[i].x);
            acc[i].y = fmaf(xv.y, w1.y, acc[i].y);
            acc[i].z = fmaf(xv.y, w1.z, acc[i].z);
            acc[i].w = fmaf(xv.y, w1.w, acc[i].w);
            acc[i].x = fmaf(xv.z, w2.x, acc[i].x);
            acc[i].y = fmaf(xv.z, w2.y, acc[i].y);
            acc[i].z = fmaf(xv.z, w2.z, acc[i].z);
            acc[i].w = fmaf(xv.z, w2.w, acc[i].w);
            acc[i].x = fmaf(xv.w, w3.x, acc[i].x);
            acc[i].y = fmaf(xv.w, w3.y, acc[i].y);
            acc[i].z = fmaf(xv.w, w3.z, acc[i].z);
            acc[i].w = fmaf(xv.w, w3.w, acc[i].w);
        }
    }

    #pragma unroll
    for (int i = 0; i < 8; ++i) {
        int gr = row0 + rg + i;
        if (gr < n) {
            ushort4 o;
            o.x = f2bf(acc[i].x);
            o.y = f2bf(acc[i].y);
            o.z = f2bf(acc[i].z);
            o.w = f2bf(acc[i].w);
            *(ushort4*)&Y[(size_t)gr * HD + cg] = o;
        }
    }
}

// ---------------- Aggregation, feature-sliced (bf16 gather, f32 accumulate) ----------------
// grid.x = 4*nbn; slice = bid/nbn covers features [slice*32, slice*32+32) = 64B/row.
// Blocks dispatch in ascending order, so the resident window works one slice at a
// time: active hin footprint = 50000*64B = 3.2MB < 4MB per-XCD L2.
// Wave = 1 node; lane quarter q handles edges e0+q, e0+q+4, ... (no divergence);
// lane-in-quarter owns 2 features; cross-quarter shfl_xor reduce at the end.

__global__ __launch_bounds__(256) void k_agg(const unsigned short* __restrict__ hin,
                                             const int2* __restrict__ ecol,
                                             const float* __restrict__ dinv,
                                             const int* __restrict__ row_start,
                                             const float* __restrict__ bias,
                                             float* __restrict__ hout, int n, int nbn) {
    int slice = blockIdx.x / nbn;
    int nblk  = blockIdx.x % nbn;
    int wave = threadIdx.x >> 6;
    int lane = threadIdx.x & 63;
    int v = nblk * 4 + wave;
    if (v >= n) return;

    int q = lane >> 4;              // edge quarter 0..3
    int l = lane & 15;              // feature-pair lane within quarter
    int f = slice * 32 + l * 2;

    float accx = 0.f, accy = 0.f;
    int e0 = row_start[v], e1 = row_start[v + 1];

    int e = e0 + q;
    for (; e + 4 < e1; e += 8) {    // two edges per quarter per iter
        int2 pa = ecol[e];
        int2 pb = ecol[e + 4];
        ushort2 aa = *(const ushort2*)(hin + (size_t)pa.x * HD + f);
        ushort2 ab = *(const ushort2*)(hin + (size_t)pb.x * HD + f);
        float wa = __int_as_float(pa.y);
        float wb = __int_as_float(pb.y);
        accx = fmaf(bf2f(aa.x), wa, accx); accy = fmaf(bf2f(aa.y), wa, accy);
        accx = fmaf(bf2f(ab.x), wb, accx); accy = fmaf(bf2f(ab.y), wb, accy);
    }
    if (e < e1) {
        int2 p = ecol[e];
        ushort2 a = *(const ushort2*)(hin + (size_t)p.x * HD + f);
        float w = __int_as_float(p.y);
        accx = fmaf(bf2f(a.x), w, accx); accy = fmaf(bf2f(a.y), w, accy);
    }

    // combine quarters: lanes {l, l+16, l+32, l+48}
    accx += __shfl_xor(accx, 16); accy += __shfl_xor(accy, 16);
    accx += __shfl_xor(accx, 32); accy += __shfl_xor(accy, 32);

    if (q == 0) {
        float dv = dinv[v];
        float selfw = dv * dv;
        ushort2 sv = *(const ushort2*)(hin + (size_t)v * HD + f);
        float2 b = *(const float2*)(bias + f);
        float2 o;
        o.x = fmaxf(fmaf(bf2f(sv.x), selfw, accx) + b.x, 0.f);
        o.y = fmaxf(fmaf(bf2f(sv.y), selfw, accy) + b.y, 0.f);
        *(float2*)(hout + (size_t)v * HD + f) = o;
    }
}

// ---------------- Mean-pool stage 1: per-chunk segmented partial sums ----------------

#define POOL_ROWS 32

__global__ __launch_bounds__(128) void k_pool_partial(const float* __restrict__ h,
                                                      const int* __restrict__ batch,
                                                      float* __restrict__ sums, int n) {
    __shared__ int bs[POOL_ROWS];
    int t = threadIdx.x;
    int r0 = blockIdx.x * POOL_ROWS;
    int r1 = min(r0 + POOL_ROWS, n);
    int cnt = r1 - r0;
    if (t < cnt) bs[t] = batch[r0 + t];
    __syncthreads();

    int g = bs[0];
    float acc = 0.f;
    for (int i = 0; i < cnt; ++i) {
        int bg = bs[i];
        if (bg != g) {
            atomicAdd(&sums[(size_t)g * HD + t], acc);
            acc = 0.f;
            g = bg;
        }
        acc += h[(size_t)(r0 + i) * HD + t];
    }
    atomicAdd(&sums[(size_t)g * HD + t], acc);
}

// ---------------- Mean-pool stage 2: mean + FC ----------------

__global__ __launch_bounds__(128) void k_fc(const float* __restrict__ sums,
                                            const int* __restrict__ batch,
                                            const float* __restrict__ Wfc,
                                            const float* __restrict__ bfc,
                                            float* __restrict__ out, int n) {
    int g = blockIdx.x;
    int t = threadIdx.x;
    __shared__ int slo, shi;
    if (t == 0) {
        int lo = 0, hi = n;
        while (lo < hi) { int m = (lo + hi) >> 1; if (batch[m] < g) lo = m + 1; else hi = m; }
        slo = lo;
        lo = 0; hi = n;
        while (lo < hi) { int m = (lo + hi) >> 1; if (batch[m] < g + 1) lo = m + 1; else hi = m; }
        shi = lo;
    }
    __syncthreads();
    float cnt = (float)(shi - slo);
    __shared__ float sp[HD];
    sp[t] = sums[(size_t)g * HD + t] / fmaxf(cnt, 1.f);
    __syncthreads();
    if (t < NL) {
        float o = bfc[t];
        for (int k = 0; k < HD; ++k) o = fmaf(sp[k], Wfc[k * NL + t], o);
        out[g * NL + t] = o;
    }
}

// ---------------- launch ----------------

extern "C" void kernel_launch(void* const* d_in, const int* in_sizes, int n_in,
                              void* d_out, int out_size, void* d_ws, size_t ws_size,
                              hipStream_t stream) {
    const float* x    = (const float*)d_in[0];
    const int*   ei   = (const int*)d_in[1];
    const int*   batch= (const int*)d_in[2];
    const float* W1   = (const float*)d_in[3];
    const float* b1   = (const float*)d_in[4];
    const float* W2   = (const float*)d_in[5];
    const float* b2   = (const float*)d_in[6];
    const float* Wfc  = (const float*)d_in[7];
    const float* bfc  = (const float*)d_in[8];
    float* out = (float*)d_out;

    int n = in_sizes[0] / HD;       // 50000
    int E = in_sizes[1] / 2;        // 800000
    int G = out_size / NL;          // 128
    const int* srcp = ei;
    const int* dstp = ei + E;

    int nb = (n + 255) >> 8;        // 196 buckets of 256 dst nodes

    char* ws = (char*)d_ws;
    auto align256 = [](size_t v) { return (v + 255) & ~(size_t)255; };
    size_t o = 0;
    int*   row_start = (int*)(ws + o); o = align256(o + (size_t)(n + 1) * 4);
    int*   bbase     = (int*)(ws + o); o = align256(o + (size_t)(nb + 1) * 4);
    int*   gbcur     = (int*)(ws + o); o = align256(o + (size_t)nb * 4);
    float* dinv      = (float*)(ws + o); o = align256(o + (size_t)n * 4);
    int*   col       = (int*)(ws + o); o = align256(o + (size_t)E * 4);
    int2*  ecol      = (int2*)(ws + o); o = align256(o + (size_t)E * 8);
    unsigned short* tmp = (unsigned short*)(ws + o); o = align256(o + (size_t)n * HD * 2);
    float* hbuf      = (float*)(ws + o); o = align256(o + (size_t)n * HD * 4);
    float* sums      = (float*)(ws + o); o = align256(o + (size_t)G * HD * 4);

    // stage aliases hbuf: consumed by k_build before hbuf's first write (k_agg #1)
    int* stage = (int*)hbuf;        // needs nb*BCAP*4 = 4.8MB <= 25.6MB

    int mZero = G * HD;             // 16384 floats of sums
    k_zero<<<(mZero + 255) / 256, 256, 0, stream>>>(gbcur, nb, sums, mZero);

    int nblkC = (E + 4095) / 4096;  // 196
    k_bucket<<<nblkC, 256, 0, stream>>>(srcp, dstp, E, gbcur, stage, nb);
    k_bscan <<<1, 256, 0, stream>>>(gbcur, bbase, nb, row_start, n);
    k_build <<<nb, 256, 0, stream>>>(stage, gbcur, bbase, col, row_start, dinv, n);
    k_wnorm <<<(n * 16 + 255) / 256, 256, 0, stream>>>(col, row_start, dinv, ecol, n);

    int nbn = (n + 3) / 4;          // node-blocks per slice
    k_gemm128<<<(n + 63) / 64, 256, 0, stream>>>(x, W1, tmp, n);
    k_agg    <<<4 * nbn, 256, 0, stream>>>(tmp, ecol, dinv, row_start, b1, hbuf, n, nbn);
    k_gemm128<<<(n + 63) / 64, 256, 0, stream>>>(hbuf, W2, tmp, n);
    k_agg    <<<4 * nbn, 256, 0, stream>>>(tmp, ecol, dinv, row_start, b2, hbuf, n, nbn);

    k_pool_partial<<<(n + POOL_ROWS - 1) / POOL_ROWS, 128, 0, stream>>>(hbuf, batch, sums, n);
    k_fc<<<G, 128, 0, stream>>>(sums, batch, Wfc, bfc, out, n);
}

// Round 10
// 243.278 us; speedup vs baseline: 1.2103x; 1.2103x over previous
//
#include <hip/hip_runtime.h>
#include <hip/hip_bf16.h>

#define HD 128   // hidden/feature dim
#define NL 7     // label dim
#define BCAP 6144  // per-bucket stage capacity (avg 4082 for E=800K/196 buckets; +50% headroom)

__device__ __forceinline__ unsigned short f2bf(float f) {
    __hip_bfloat16 b = __float2bfloat16(f);   // RNE
    return *reinterpret_cast<unsigned short*>(&b);
}
__device__ __forceinline__ float bf2f(unsigned short u) {
    unsigned int x = ((unsigned int)u) << 16;
    return __uint_as_float(x);
}

// ---------------- workspace zeroing ----------------

__global__ __launch_bounds__(256) void k_zero(int* __restrict__ gbcur, int nb,
                                              float* __restrict__ sums, int m) {
    int i = blockIdx.x * 256 + threadIdx.x;
    if (i < nb) gbcur[i] = 0;
    if (i < m) sums[i] = 0.f;
}

// ---------------- CSR build via bucketed counting sort ----------------

__global__ __launch_bounds__(256) void k_bucket(const int* __restrict__ src,
                                                const int* __restrict__ dst, int E,
                                                int* __restrict__ gbcur,
                                                int* __restrict__ stage, int nb) {
    __shared__ int lh[256];
    __shared__ int gb[256];
    int t = threadIdx.x;
    if (t < nb) lh[t] = 0;
    __syncthreads();

    int e0 = blockIdx.x * 4096;
    int bk[16]; int lr[16]; int rec[16];
    #pragma unroll
    for (int j = 0; j < 16; ++j) {
        int e = e0 + j * 256 + t;
        if (e < E) {
            int d = dst[e];
            int s = src[e];
            bk[j]  = d >> 8;
            rec[j] = ((d & 255) << 16) | s;       // src < 65536
            lr[j]  = atomicAdd(&lh[bk[j]], 1);    // local rank
        } else {
            bk[j] = -1; lr[j] = 0; rec[j] = 0;
        }
    }
    __syncthreads();
    if (t < nb) gb[t] = atomicAdd(&gbcur[t], lh[t]);   // reserve run per bucket
    __syncthreads();
    #pragma unroll
    for (int j = 0; j < 16; ++j) {
        if (bk[j] >= 0) {
            int p = gb[bk[j]] + lr[j];
            if (p < BCAP) stage[bk[j] * BCAP + p] = rec[j];
        }
    }
}

__global__ __launch_bounds__(256) void k_bscan(const int* __restrict__ gbcnt,
                                               int* __restrict__ bbase, int nb,
                                               int* __restrict__ row_start, int n) {
    __shared__ int s[256];
    int t = threadIdx.x;
    int val = (t < nb) ? gbcnt[t] : 0;
    s[t] = val;
    __syncthreads();
    #pragma unroll
    for (int off = 1; off < 256; off <<= 1) {
        int v = (t >= off) ? s[t - off] : 0;
        __syncthreads();
        s[t] += v;
        __syncthreads();
    }
    if (t < nb) bbase[t] = s[t] - val;
    if (t == 255) { bbase[nb] = s[255]; row_start[n] = s[255]; }
}

__global__ __launch_bounds__(256) void k_build(const int* __restrict__ stage,
                                               const int* __restrict__ gbcnt,
                                               const int* __restrict__ bbase,
                                               int* __restrict__ col,
                                               int* __restrict__ row_start,
                                               float* __restrict__ dinv, int n) {
    __shared__ int rec_s[BCAP];
    __shared__ unsigned short rank_s[BCAP];
    __shared__ int hist[256];
    __shared__ int scan_s[256];
    int b = blockIdx.x, t = threadIdx.x;
    int cnt  = min(gbcnt[b], BCAP);
    int base = bbase[b];
    int node0 = b << 8;

    hist[t] = 0;
    __syncthreads();
    for (int e = t; e < cnt; e += 256) {
        int r = stage[b * BCAP + e];
        rec_s[e] = r;
        rank_s[e] = (unsigned short)atomicAdd(&hist[r >> 16], 1);
    }
    __syncthreads();

    int deg = hist[t];
    int node = node0 + t;
    if (node < n) dinv[node] = 1.0f / sqrtf((float)(deg + 1));  // +1 self loop

    scan_s[t] = deg;
    __syncthreads();
    #pragma unroll
    for (int off = 1; off < 256; off <<= 1) {
        int v = (t >= off) ? scan_s[t - off] : 0;
        __syncthreads();
        scan_s[t] += v;
        __syncthreads();
    }
    int lrs = scan_s[t] - deg;      // local exclusive prefix
    hist[t] = lrs;                  // reuse hist as lrs table
    if (node < n) row_start[node] = base + lrs;
    __syncthreads();

    for (int e = t; e < cnt; e += 256) {
        int r = rec_s[e];
        col[base + hist[r >> 16] + rank_s[e]] = r & 0xFFFF;
    }
}

// ---------------- per-edge weight precompute: ecol[e] = {src, dinv[src]*dinv[dst]} ----------

__global__ __launch_bounds__(256) void k_wnorm(const int* __restrict__ col,
                                               const int* __restrict__ row_start,
                                               const float* __restrict__ dinv,
                                               int2* __restrict__ ecol, int n) {
    int tid = blockIdx.x * 256 + threadIdx.x;
    int node = tid >> 4;
    int l = tid & 15;
    if (node >= n) return;
    float dv = dinv[node];
    int e1 = row_start[node + 1];
    for (int e = row_start[node] + l; e < e1; e += 16) {
        int s = col[e];
        int2 p;
        p.x = s;
        p.y = __float_as_int(dinv[s] * dv);
        ecol[e] = p;
    }
}

// ---------------- GEMM: Y[n,128](bf16) = X[n,128](f32|bf16) @ W[128,128](f32) ----------------

template <typename TIN>
__global__ __launch_bounds__(256) void k_gemm128(const TIN* __restrict__ X,
                                                 const float* __restrict__ W,
                                                 unsigned short* __restrict__ Y, int n) {
    __shared__ float xs[64][HD];
    int tid = threadIdx.x;
    int row0 = blockIdx.x * 64;

    #pragma unroll
    for (int j = 0; j < 8; ++j) {
        int f4 = tid + j * 256;        // 0..2047 (4-element chunks)
        int r = f4 >> 5;               // 32 chunks per row
        int c = (f4 & 31) * 4;
        int gr = row0 + r;
        float4 v = make_float4(0.f, 0.f, 0.f, 0.f);
        if (gr < n) {
            if constexpr (sizeof(TIN) == 4) {
                v = *(const float4*)&X[(size_t)gr * HD + c];
            } else {
                ushort4 u = *(const ushort4*)&X[(size_t)gr * HD + c];
                v.x = bf2f(u.x); v.y = bf2f(u.y); v.z = bf2f(u.z); v.w = bf2f(u.w);
            }
        }
        *(float4*)&xs[r][c] = v;
    }
    __syncthreads();

    int cg = (tid & 31) * 4;
    int rg = (tid >> 5) * 8;

    float4 acc[8];
    #pragma unroll
    for (int i = 0; i < 8; ++i) acc[i] = make_float4(0.f, 0.f, 0.f, 0.f);

    for (int k = 0; k < HD; k += 4) {
        float4 w0 = *(const float4*)&W[(size_t)(k + 0) * HD + cg];
        float4 w1 = *(const float4*)&W[(size_t)(k + 1) * HD + cg];
        float4 w2 = *(const float4*)&W[(size_t)(k + 2) * HD + cg];
        float4 w3 = *(const float4*)&W[(size_t)(k + 3) * HD + cg];
        #pragma unroll
        for (int i = 0; i < 8; ++i) {
            float4 xv = *(const float4*)&xs[rg + i][k];
            acc[i].x = fmaf(xv.x, w0.x, acc[i].x);
            acc[i].y = fmaf(xv.x, w0.y, acc[i].y);
            acc[i].z = fmaf(xv.x, w0.z, acc[i].z);
            acc[i].w = fmaf(xv.x, w0.w, acc[i].w);
            acc[i].x = fmaf(xv.y, w1.x, acc[i].x);
            acc[i].y = fmaf(xv.y, w1.y, acc[i].y);
            acc[i].z = fmaf(xv.y, w1.z, acc[i].z);
            acc[i].w = fmaf(xv.y, w1.w, acc[i].w);
            acc[i].x = fmaf(xv.z, w2.x, acc[i].x);
            acc[i].y = fmaf(xv.z, w2.y, acc[i].y);
            acc[i].z = fmaf(xv.z, w2.z, acc[i].z);
            acc[i].w = fmaf(xv.z, w2.w, acc[i].w);
            acc[i].x = fmaf(xv.w, w3.x, acc[i].x);
            acc[i].y = fmaf(xv.w, w3.y, acc[i].y);
            acc[i].z = fmaf(xv.w, w3.z, acc[i].z);
            acc[i].w = fmaf(xv.w, w3.w, acc[i].w);
        }
    }

    #pragma unroll
    for (int i = 0; i < 8; ++i) {
        int gr = row0 + rg + i;
        if (gr < n) {
            ushort4 o;
            o.x = f2bf(acc[i].x);
            o.y = f2bf(acc[i].y);
            o.z = f2bf(acc[i].z);
            o.w = f2bf(acc[i].w);
            *(ushort4*)&Y[(size_t)gr * HD + cg] = o;
        }
    }
}

// ---------------- Aggregation (bf16 gather, f32 accumulate) ----------------
// MODE 0: out = relu(agg + bias) written as bf16 rows (feeds gemm2).
// MODE 1: fused mean-pool -- relu'd row atomically added into sums[batch[v]].

template <int MODE>
__global__ __launch_bounds__(256) void k_agg(const unsigned short* __restrict__ hin,
                                             const int2* __restrict__ ecol,
                                             const float* __restrict__ dinv,
                                             const int* __restrict__ row_start,
                                             const float* __restrict__ bias,
                                             unsigned short* __restrict__ hout,
                                             const int* __restrict__ batch,
                                             float* __restrict__ sums, int n) {
    int wave = threadIdx.x >> 6;
    int lane = threadIdx.x & 63;
    int v = blockIdx.x * 4 + wave;
    if (v >= n) return;

    float dv = dinv[v];
    int f = lane * 2;
    ushort2 sv = *(const ushort2*)(hin + (size_t)v * HD + f);
    float selfw = dv * dv;
    float accx = bf2f(sv.x) * selfw;
    float accy = bf2f(sv.y) * selfw;

    int e  = row_start[v];
    int e1 = row_start[v + 1];

    for (; e + 8 <= e1; e += 8) {
        int2 p0 = ecol[e],   p1 = ecol[e+1], p2 = ecol[e+2], p3 = ecol[e+3];
        int2 p4 = ecol[e+4], p5 = ecol[e+5], p6 = ecol[e+6], p7 = ecol[e+7];
        ushort2 a0 = *(const ushort2*)(hin + (size_t)p0.x * HD + f);
        ushort2 a1 = *(const ushort2*)(hin + (size_t)p1.x * HD + f);
        ushort2 a2 = *(const ushort2*)(hin + (size_t)p2.x * HD + f);
        ushort2 a3 = *(const ushort2*)(hin + (size_t)p3.x * HD + f);
        ushort2 a4 = *(const ushort2*)(hin + (size_t)p4.x * HD + f);
        ushort2 a5 = *(const ushort2*)(hin + (size_t)p5.x * HD + f);
        ushort2 a6 = *(const ushort2*)(hin + (size_t)p6.x * HD + f);
        ushort2 a7 = *(const ushort2*)(hin + (size_t)p7.x * HD + f);
        float w0 = __int_as_float(p0.y), w1 = __int_as_float(p1.y);
        float w2 = __int_as_float(p2.y), w3 = __int_as_float(p3.y);
        float w4 = __int_as_float(p4.y), w5 = __int_as_float(p5.y);
        float w6 = __int_as_float(p6.y), w7 = __int_as_float(p7.y);
        accx = fmaf(bf2f(a0.x), w0, accx); accy = fmaf(bf2f(a0.y), w0, accy);
        accx = fmaf(bf2f(a1.x), w1, accx); accy = fmaf(bf2f(a1.y), w1, accy);
        accx = fmaf(bf2f(a2.x), w2, accx); accy = fmaf(bf2f(a2.y), w2, accy);
        accx = fmaf(bf2f(a3.x), w3, accx); accy = fmaf(bf2f(a3.y), w3, accy);
        accx = fmaf(bf2f(a4.x), w4, accx); accy = fmaf(bf2f(a4.y), w4, accy);
        accx = fmaf(bf2f(a5.x), w5, accx); accy = fmaf(bf2f(a5.y), w5, accy);
        accx = fmaf(bf2f(a6.x), w6, accx); accy = fmaf(bf2f(a6.y), w6, accy);
        accx = fmaf(bf2f(a7.x), w7, accx); accy = fmaf(bf2f(a7.y), w7, accy);
    }

    {   // predicated tail
        int rem = e1 - e;
        int2 p[7]; ushort2 a[7];
        #pragma unroll
        for (int j = 0; j < 7; ++j) {
            if (j < rem) {
                p[j] = ecol[e + j];
                a[j] = *(const ushort2*)(hin + (size_t)p[j].x * HD + f);
            }
        }
        #pragma unroll
        for (int j = 0; j < 7; ++j) {
            if (j < rem) {
                float w = __int_as_float(p[j].y);
                accx = fmaf(bf2f(a[j].x), w, accx);
                accy = fmaf(bf2f(a[j].y), w, accy);
            }
        }
    }

    float2 b = *(const float2*)(bias + f);
    float ox = fmaxf(accx + b.x, 0.f);
    float oy = fmaxf(accy + b.y, 0.f);

    if constexpr (MODE == 0) {
        ushort2 o;
        o.x = f2bf(ox);
        o.y = f2bf(oy);
        *(ushort2*)(hout + (size_t)v * HD + f) = o;
    } else {
        int g = batch[v];
        float* sp = sums + (size_t)g * HD + f;
        atomicAdd(sp,     ox);
        atomicAdd(sp + 1, oy);
    }
}

// ---------------- mean + FC (sums already hold per-graph totals) ----------------

__global__ __launch_bounds__(128) void k_fc(const float* __restrict__ sums,
                                            const int* __restrict__ batch,
                                            const float* __restrict__ Wfc,
                                            const float* __restrict__ bfc,
                                            float* __restrict__ out, int n) {
    int g = blockIdx.x;
    int t = threadIdx.x;
    __shared__ int slo, shi;
    if (t == 0) {
        int lo = 0, hi = n;
        while (lo < hi) { int m = (lo + hi) >> 1; if (batch[m] < g) lo = m + 1; else hi = m; }
        slo = lo;
        lo = 0; hi = n;
        while (lo < hi) { int m = (lo + hi) >> 1; if (batch[m] < g + 1) lo = m + 1; else hi = m; }
        shi = lo;
    }
    __syncthreads();
    float cnt = (float)(shi - slo);
    __shared__ float sp[HD];
    sp[t] = sums[(size_t)g * HD + t] / fmaxf(cnt, 1.f);
    __syncthreads();
    if (t < NL) {
        float o = bfc[t];
        for (int k = 0; k < HD; ++k) o = fmaf(sp[k], Wfc[k * NL + t], o);
        out[g * NL + t] = o;
    }
}

// ---------------- launch ----------------

extern "C" void kernel_launch(void* const* d_in, const int* in_sizes, int n_in,
                              void* d_out, int out_size, void* d_ws, size_t ws_size,
                              hipStream_t stream) {
    const float* x    = (const float*)d_in[0];
    const int*   ei   = (const int*)d_in[1];
    const int*   batch= (const int*)d_in[2];
    const float* W1   = (const float*)d_in[3];
    const float* b1   = (const float*)d_in[4];
    const float* W2   = (const float*)d_in[5];
    const float* b2   = (const float*)d_in[6];
    const float* Wfc  = (const float*)d_in[7];
    const float* bfc  = (const float*)d_in[8];
    float* out = (float*)d_out;

    int n = in_sizes[0] / HD;       // 50000
    int E = in_sizes[1] / 2;        // 800000
    int G = out_size / NL;          // 128
    const int* srcp = ei;
    const int* dstp = ei + E;

    int nb = (n + 255) >> 8;        // 196 buckets of 256 dst nodes

    char* ws = (char*)d_ws;
    auto align256 = [](size_t v) { return (v + 255) & ~(size_t)255; };
    size_t o = 0;
    int*   row_start = (int*)(ws + o); o = align256(o + (size_t)(n + 1) * 4);
    int*   bbase     = (int*)(ws + o); o = align256(o + (size_t)(nb + 1) * 4);
    int*   gbcur     = (int*)(ws + o); o = align256(o + (size_t)nb * 4);
    float* dinv      = (float*)(ws + o); o = align256(o + (size_t)n * 4);
    int*   col       = (int*)(ws + o); o = align256(o + (size_t)E * 4);
    int2*  ecol      = (int2*)(ws + o); o = align256(o + (size_t)E * 8);
    unsigned short* tmp  = (unsigned short*)(ws + o); o = align256(o + (size_t)n * HD * 2);
    unsigned short* tmp2 = (unsigned short*)(ws + o); o = align256(o + (size_t)n * HD * 2);
    int*   stage     = (int*)(ws + o); o = align256(o + (size_t)nb * BCAP * 4);
    float* sums      = (float*)(ws + o); o = align256(o + (size_t)G * HD * 4);

    int mZero = G * HD;             // 16384 floats of sums
    k_zero<<<(mZero + 255) / 256, 256, 0, stream>>>(gbcur, nb, sums, mZero);

    int nblkC = (E + 4095) / 4096;  // 196
    k_bucket<<<nblkC, 256, 0, stream>>>(srcp, dstp, E, gbcur, stage, nb);
    k_bscan <<<1, 256, 0, stream>>>(gbcur, bbase, nb, row_start, n);
    k_build <<<nb, 256, 0, stream>>>(stage, gbcur, bbase, col, row_start, dinv, n);
    k_wnorm <<<(n * 16 + 255) / 256, 256, 0, stream>>>(col, row_start, dinv, ecol, n);

    k_gemm128<float><<<(n + 63) / 64, 256, 0, stream>>>(x, W1, tmp, n);
    k_agg<0><<<(n + 3) / 4, 256, 0, stream>>>(tmp, ecol, dinv, row_start, b1,
                                              tmp2, nullptr, nullptr, n);
    k_gemm128<unsigned short><<<(n + 63) / 64, 256, 0, stream>>>(tmp2, W2, tmp, n);
    k_agg<1><<<(n + 3) / 4, 256, 0, stream>>>(tmp, ecol, dinv, row_start, b2,
                                              nullptr, batch, sums, n);

    k_fc<<<G, 128, 0, stream>>>(sums, batch, Wfc, bfc, out, n);
}

// Round 11
// 193.443 us; speedup vs baseline: 1.5221x; 1.2576x over previous
//
#include <hip/hip_runtime.h>
#include <hip/hip_bf16.h>

#define HD 128   // hidden/feature dim
#define NL 7     // label dim
#define BCAP 6144  // per-bucket stage capacity (avg 4082 for E=800K/196 buckets; +50% headroom)

__device__ __forceinline__ unsigned short f2bf(float f) {
    __hip_bfloat16 b = __float2bfloat16(f);   // RNE
    return *reinterpret_cast<unsigned short*>(&b);
}
__device__ __forceinline__ float bf2f(unsigned short u) {
    unsigned int x = ((unsigned int)u) << 16;
    return __uint_as_float(x);
}

// ---------------- workspace zeroing ----------------

__global__ __launch_bounds__(256) void k_zero(int* __restrict__ gbcur, int nb,
                                              float* __restrict__ sums, int m) {
    int i = blockIdx.x * 256 + threadIdx.x;
    if (i < nb) gbcur[i] = 0;
    if (i < m) sums[i] = 0.f;
}

// ---------------- CSR build via bucketed counting sort ----------------

__global__ __launch_bounds__(256) void k_bucket(const int* __restrict__ src,
                                                const int* __restrict__ dst, int E,
                                                int* __restrict__ gbcur,
                                                int* __restrict__ stage, int nb) {
    __shared__ int lh[256];
    __shared__ int gb[256];
    int t = threadIdx.x;
    if (t < nb) lh[t] = 0;
    __syncthreads();

    int e0 = blockIdx.x * 4096;
    int bk[16]; int lr[16]; int rec[16];
    #pragma unroll
    for (int j = 0; j < 16; ++j) {
        int e = e0 + j * 256 + t;
        if (e < E) {
            int d = dst[e];
            int s = src[e];
            bk[j]  = d >> 8;
            rec[j] = ((d & 255) << 16) | s;       // src < 65536
            lr[j]  = atomicAdd(&lh[bk[j]], 1);    // local rank
        } else {
            bk[j] = -1; lr[j] = 0; rec[j] = 0;
        }
    }
    __syncthreads();
    if (t < nb) gb[t] = atomicAdd(&gbcur[t], lh[t]);   // reserve run per bucket
    __syncthreads();
    #pragma unroll
    for (int j = 0; j < 16; ++j) {
        if (bk[j] >= 0) {
            int p = gb[bk[j]] + lr[j];
            if (p < BCAP) stage[bk[j] * BCAP + p] = rec[j];
        }
    }
}

__global__ __launch_bounds__(256) void k_bscan(const int* __restrict__ gbcnt,
                                               int* __restrict__ bbase, int nb,
                                               int* __restrict__ row_start, int n) {
    __shared__ int s[256];
    int t = threadIdx.x;
    int val = (t < nb) ? gbcnt[t] : 0;
    s[t] = val;
    __syncthreads();
    #pragma unroll
    for (int off = 1; off < 256; off <<= 1) {
        int v = (t >= off) ? s[t - off] : 0;
        __syncthreads();
        s[t] += v;
        __syncthreads();
    }
    if (t < nb) bbase[t] = s[t] - val;
    if (t == 255) { bbase[nb] = s[255]; row_start[n] = s[255]; }
}

__global__ __launch_bounds__(256) void k_build(const int* __restrict__ stage,
                                               const int* __restrict__ gbcnt,
                                               const int* __restrict__ bbase,
                                               int* __restrict__ col,
                                               int* __restrict__ row_start,
                                               float* __restrict__ dinv, int n) {
    __shared__ int rec_s[BCAP];
    __shared__ unsigned short rank_s[BCAP];
    __shared__ int hist[256];
    __shared__ int scan_s[256];
    int b = blockIdx.x, t = threadIdx.x;
    int cnt  = min(gbcnt[b], BCAP);
    int base = bbase[b];
    int node0 = b << 8;

    hist[t] = 0;
    __syncthreads();
    for (int e = t; e < cnt; e += 256) {
        int r = stage[b * BCAP + e];
        rec_s[e] = r;
        rank_s[e] = (unsigned short)atomicAdd(&hist[r >> 16], 1);
    }
    __syncthreads();

    int deg = hist[t];
    int node = node0 + t;
    if (node < n) dinv[node] = 1.0f / sqrtf((float)(deg + 1));  // +1 self loop

    scan_s[t] = deg;
    __syncthreads();
    #pragma unroll
    for (int off = 1; off < 256; off <<= 1) {
        int v = (t >= off) ? scan_s[t - off] : 0;
        __syncthreads();
        scan_s[t] += v;
        __syncthreads();
    }
    int lrs = scan_s[t] - deg;      // local exclusive prefix
    hist[t] = lrs;                  // reuse hist as lrs table
    if (node < n) row_start[node] = base + lrs;
    __syncthreads();

    for (int e = t; e < cnt; e += 256) {
        int r = rec_s[e];
        col[base + hist[r >> 16] + rank_s[e]] = r & 0xFFFF;
    }
}

// ---------------- per-edge weight precompute: ecol[e] = {src, dinv[src]*dinv[dst]} ----------

__global__ __launch_bounds__(256) void k_wnorm(const int* __restrict__ col,
                                               const int* __restrict__ row_start,
                                               const float* __restrict__ dinv,
                                               int2* __restrict__ ecol, int n) {
    int tid = blockIdx.x * 256 + threadIdx.x;
    int node = tid >> 4;
    int l = tid & 15;
    if (node >= n) return;
    float dv = dinv[node];
    int e1 = row_start[node + 1];
    for (int e = row_start[node] + l; e < e1; e += 16) {
        int s = col[e];
        int2 p;
        p.x = s;
        p.y = __float_as_int(dinv[s] * dv);
        ecol[e] = p;
    }
}

// ---------------- GEMM: Y[n,128](bf16) = X[n,128](f32|bf16) @ W[128,128](f32) ----------------

template <typename TIN>
__global__ __launch_bounds__(256) void k_gemm128(const TIN* __restrict__ X,
                                                 const float* __restrict__ W,
                                                 unsigned short* __restrict__ Y, int n) {
    __shared__ float xs[64][HD];
    int tid = threadIdx.x;
    int row0 = blockIdx.x * 64;

    #pragma unroll
    for (int j = 0; j < 8; ++j) {
        int f4 = tid + j * 256;        // 0..2047 (4-element chunks)
        int r = f4 >> 5;               // 32 chunks per row
        int c = (f4 & 31) * 4;
        int gr = row0 + r;
        float4 v = make_float4(0.f, 0.f, 0.f, 0.f);
        if (gr < n) {
            if constexpr (sizeof(TIN) == 4) {
                v = *(const float4*)&X[(size_t)gr * HD + c];
            } else {
                ushort4 u = *(const ushort4*)&X[(size_t)gr * HD + c];
                v.x = bf2f(u.x); v.y = bf2f(u.y); v.z = bf2f(u.z); v.w = bf2f(u.w);
            }
        }
        *(float4*)&xs[r][c] = v;
    }
    __syncthreads();

    int cg = (tid & 31) * 4;
    int rg = (tid >> 5) * 8;

    float4 acc[8];
    #pragma unroll
    for (int i = 0; i < 8; ++i) acc[i] = make_float4(0.f, 0.f, 0.f, 0.f);

    for (int k = 0; k < HD; k += 4) {
        float4 w0 = *(const float4*)&W[(size_t)(k + 0) * HD + cg];
        float4 w1 = *(const float4*)&W[(size_t)(k + 1) * HD + cg];
        float4 w2 = *(const float4*)&W[(size_t)(k + 2) * HD + cg];
        float4 w3 = *(const float4*)&W[(size_t)(k + 3) * HD + cg];
        #pragma unroll
        for (int i = 0; i < 8; ++i) {
            float4 xv = *(const float4*)&xs[rg + i][k];
            acc[i].x = fmaf(xv.x, w0.x, acc[i].x);
            acc[i].y = fmaf(xv.x, w0.y, acc[i].y);
            acc[i].z = fmaf(xv.x, w0.z, acc[i].z);
            acc[i].w = fmaf(xv.x, w0.w, acc[i].w);
            acc[i].x = fmaf(xv.y, w1.x, acc[i].x);
            acc[i].y = fmaf(xv.y, w1.y, acc[i].y);
            acc[i].z = fmaf(xv.y, w1.z, acc[i].z);
            acc[i].w = fmaf(xv.y, w1.w, acc[i].w);
            acc[i].x = fmaf(xv.z, w2.x, acc[i].x);
            acc[i].y = fmaf(xv.z, w2.y, acc[i].y);
            acc[i].z = fmaf(xv.z, w2.z, acc[i].z);
            acc[i].w = fmaf(xv.z, w2.w, acc[i].w);
            acc[i].x = fmaf(xv.w, w3.x, acc[i].x);
            acc[i].y = fmaf(xv.w, w3.y, acc[i].y);
            acc[i].z = fmaf(xv.w, w3.z, acc[i].z);
            acc[i].w = fmaf(xv.w, w3.w, acc[i].w);
        }
    }

    #pragma unroll
    for (int i = 0; i < 8; ++i) {
        int gr = row0 + rg + i;
        if (gr < n) {
            ushort4 o;
            o.x = f2bf(acc[i].x);
            o.y = f2bf(acc[i].y);
            o.z = f2bf(acc[i].z);
            o.w = f2bf(acc[i].w);
            *(ushort4*)&Y[(size_t)gr * HD + cg] = o;
        }
    }
}

// ---------------- Aggregation (bf16 gather, f32 accumulate, bf16 out) ----------------
// out[v] = relu( sum h[s]*w + h[v]*dinv[v]^2 + bias ), written as bf16 rows.

__global__ __launch_bounds__(256) void k_agg(const unsigned short* __restrict__ hin,
                                             const int2* __restrict__ ecol,
                                             const float* __restrict__ dinv,
                                             const int* __restrict__ row_start,
                                             const float* __restrict__ bias,
                                             unsigned short* __restrict__ hout, int n) {
    int wave = threadIdx.x >> 6;
    int lane = threadIdx.x & 63;
    int v = blockIdx.x * 4 + wave;
    if (v >= n) return;

    float dv = dinv[v];
    int f = lane * 2;
    ushort2 sv = *(const ushort2*)(hin + (size_t)v * HD + f);
    float selfw = dv * dv;
    float accx = bf2f(sv.x) * selfw;
    float accy = bf2f(sv.y) * selfw;

    int e  = row_start[v];
    int e1 = row_start[v + 1];

    for (; e + 8 <= e1; e += 8) {
        int2 p0 = ecol[e],   p1 = ecol[e+1], p2 = ecol[e+2], p3 = ecol[e+3];
        int2 p4 = ecol[e+4], p5 = ecol[e+5], p6 = ecol[e+6], p7 = ecol[e+7];
        ushort2 a0 = *(const ushort2*)(hin + (size_t)p0.x * HD + f);
        ushort2 a1 = *(const ushort2*)(hin + (size_t)p1.x * HD + f);
        ushort2 a2 = *(const ushort2*)(hin + (size_t)p2.x * HD + f);
        ushort2 a3 = *(const ushort2*)(hin + (size_t)p3.x * HD + f);
        ushort2 a4 = *(const ushort2*)(hin + (size_t)p4.x * HD + f);
        ushort2 a5 = *(const ushort2*)(hin + (size_t)p5.x * HD + f);
        ushort2 a6 = *(const ushort2*)(hin + (size_t)p6.x * HD + f);
        ushort2 a7 = *(const ushort2*)(hin + (size_t)p7.x * HD + f);
        float w0 = __int_as_float(p0.y), w1 = __int_as_float(p1.y);
        float w2 = __int_as_float(p2.y), w3 = __int_as_float(p3.y);
        float w4 = __int_as_float(p4.y), w5 = __int_as_float(p5.y);
        float w6 = __int_as_float(p6.y), w7 = __int_as_float(p7.y);
        accx = fmaf(bf2f(a0.x), w0, accx); accy = fmaf(bf2f(a0.y), w0, accy);
        accx = fmaf(bf2f(a1.x), w1, accx); accy = fmaf(bf2f(a1.y), w1, accy);
        accx = fmaf(bf2f(a2.x), w2, accx); accy = fmaf(bf2f(a2.y), w2, accy);
        accx = fmaf(bf2f(a3.x), w3, accx); accy = fmaf(bf2f(a3.y), w3, accy);
        accx = fmaf(bf2f(a4.x), w4, accx); accy = fmaf(bf2f(a4.y), w4, accy);
        accx = fmaf(bf2f(a5.x), w5, accx); accy = fmaf(bf2f(a5.y), w5, accy);
        accx = fmaf(bf2f(a6.x), w6, accx); accy = fmaf(bf2f(a6.y), w6, accy);
        accx = fmaf(bf2f(a7.x), w7, accx); accy = fmaf(bf2f(a7.y), w7, accy);
    }

    {   // predicated tail
        int rem = e1 - e;
        int2 p[7]; ushort2 a[7];
        #pragma unroll
        for (int j = 0; j < 7; ++j) {
            if (j < rem) {
                p[j] = ecol[e + j];
                a[j] = *(const ushort2*)(hin + (size_t)p[j].x * HD + f);
            }
        }
        #pragma unroll
        for (int j = 0; j < 7; ++j) {
            if (j < rem) {
                float w = __int_as_float(p[j].y);
                accx = fmaf(bf2f(a[j].x), w, accx);
                accy = fmaf(bf2f(a[j].y), w, accy);
            }
        }
    }

    float2 b = *(const float2*)(bias + f);
    ushort2 o;
    o.x = f2bf(fmaxf(accx + b.x, 0.f));
    o.y = f2bf(fmaxf(accy + b.y, 0.f));
    *(ushort2*)(hout + (size_t)v * HD + f) = o;
}

// ---------------- Mean-pool stage 1: per-chunk segmented partial sums (bf16 in) --------

#define POOL_ROWS 32

__global__ __launch_bounds__(128) void k_pool_partial(const unsigned short* __restrict__ h,
                                                      const int* __restrict__ batch,
                                                      float* __restrict__ sums, int n) {
    __shared__ int bs[POOL_ROWS];
    int t = threadIdx.x;
    int r0 = blockIdx.x * POOL_ROWS;
    int r1 = min(r0 + POOL_ROWS, n);
    int cnt = r1 - r0;
    if (t < cnt) bs[t] = batch[r0 + t];
    __syncthreads();

    int g = bs[0];
    float acc = 0.f;
    for (int i = 0; i < cnt; ++i) {
        int bg = bs[i];
        if (bg != g) {
            atomicAdd(&sums[(size_t)g * HD + t], acc);
            acc = 0.f;
            g = bg;
        }
        acc += bf2f(h[(size_t)(r0 + i) * HD + t]);
    }
    atomicAdd(&sums[(size_t)g * HD + t], acc);
}

// ---------------- mean + FC ----------------

__global__ __launch_bounds__(128) void k_fc(const float* __restrict__ sums,
                                            const int* __restrict__ batch,
                                            const float* __restrict__ Wfc,
                                            const float* __restrict__ bfc,
                                            float* __restrict__ out, int n) {
    int g = blockIdx.x;
    int t = threadIdx.x;
    __shared__ int slo, shi;
    if (t == 0) {
        int lo = 0, hi = n;
        while (lo < hi) { int m = (lo + hi) >> 1; if (batch[m] < g) lo = m + 1; else hi = m; }
        slo = lo;
        lo = 0; hi = n;
        while (lo < hi) { int m = (lo + hi) >> 1; if (batch[m] < g + 1) lo = m + 1; else hi = m; }
        shi = lo;
    }
    __syncthreads();
    float cnt = (float)(shi - slo);
    __shared__ float sp[HD];
    sp[t] = sums[(size_t)g * HD + t] / fmaxf(cnt, 1.f);
    __syncthreads();
    if (t < NL) {
        float o = bfc[t];
        for (int k = 0; k < HD; ++k) o = fmaf(sp[k], Wfc[k * NL + t], o);
        out[g * NL + t] = o;
    }
}

// ---------------- launch ----------------

extern "C" void kernel_launch(void* const* d_in, const int* in_sizes, int n_in,
                              void* d_out, int out_size, void* d_ws, size_t ws_size,
                              hipStream_t stream) {
    const float* x    = (const float*)d_in[0];
    const int*   ei   = (const int*)d_in[1];
    const int*   batch= (const int*)d_in[2];
    const float* W1   = (const float*)d_in[3];
    const float* b1   = (const float*)d_in[4];
    const float* W2   = (const float*)d_in[5];
    const float* b2   = (const float*)d_in[6];
    const float* Wfc  = (const float*)d_in[7];
    const float* bfc  = (const float*)d_in[8];
    float* out = (float*)d_out;

    int n = in_sizes[0] / HD;       // 50000
    int E = in_sizes[1] / 2;        // 800000
    int G = out_size / NL;          // 128
    const int* srcp = ei;
    const int* dstp = ei + E;

    int nb = (n + 255) >> 8;        // 196 buckets of 256 dst nodes

    char* ws = (char*)d_ws;
    auto align256 = [](size_t v) { return (v + 255) & ~(size_t)255; };
    size_t o = 0;
    int*   row_start = (int*)(ws + o); o = align256(o + (size_t)(n + 1) * 4);
    int*   bbase     = (int*)(ws + o); o = align256(o + (size_t)(nb + 1) * 4);
    int*   gbcur     = (int*)(ws + o); o = align256(o + (size_t)nb * 4);
    float* dinv      = (float*)(ws + o); o = align256(o + (size_t)n * 4);
    int*   col       = (int*)(ws + o); o = align256(o + (size_t)E * 4);
    int2*  ecol      = (int2*)(ws + o); o = align256(o + (size_t)E * 8);
    unsigned short* tmp  = (unsigned short*)(ws + o); o = align256(o + (size_t)n * HD * 2);
    unsigned short* tmp2 = (unsigned short*)(ws + o); o = align256(o + (size_t)n * HD * 2);
    int*   stage     = (int*)(ws + o); o = align256(o + (size_t)nb * BCAP * 4);
    float* sums      = (float*)(ws + o); o = align256(o + (size_t)G * HD * 4);

    int mZero = G * HD;             // 16384 floats of sums
    k_zero<<<(mZero + 255) / 256, 256, 0, stream>>>(gbcur, nb, sums, mZero);

    int nblkC = (E + 4095) / 4096;  // 196
    k_bucket<<<nblkC, 256, 0, stream>>>(srcp, dstp, E, gbcur, stage, nb);
    k_bscan <<<1, 256, 0, stream>>>(gbcur, bbase, nb, row_start, n);
    k_build <<<nb, 256, 0, stream>>>(stage, gbcur, bbase, col, row_start, dinv, n);
    k_wnorm <<<(n * 16 + 255) / 256, 256, 0, stream>>>(col, row_start, dinv, ecol, n);

    k_gemm128<float><<<(n + 63) / 64, 256, 0, stream>>>(x, W1, tmp, n);
    k_agg<<<(n + 3) / 4, 256, 0, stream>>>(tmp, ecol, dinv, row_start, b1, tmp2, n);
    k_gemm128<unsigned short><<<(n + 63) / 64, 256, 0, stream>>>(tmp2, W2, tmp, n);
    k_agg<<<(n + 3) / 4, 256, 0, stream>>>(tmp, ecol, dinv, row_start, b2, tmp2, n);

    k_pool_partial<<<(n + POOL_ROWS - 1) / POOL_ROWS, 128, 0, stream>>>(tmp2, batch, sums, n);
    k_fc<<<G, 128, 0, stream>>>(sums, batch, Wfc, bfc, out, n);
}

// Round 12
// 183.841 us; speedup vs baseline: 1.6016x; 1.0522x over previous
//
#include <hip/hip_runtime.h>
#include <hip/hip_bf16.h>

#define HD 128   // hidden/feature dim
#define NL 7     // label dim
#define BCAP 6144  // per-bucket stage capacity (avg 4082 for E=800K/196 buckets; +50% headroom)

typedef __attribute__((ext_vector_type(8))) short bf16x8;
typedef __attribute__((ext_vector_type(4))) float f32x4;

__device__ __forceinline__ unsigned short f2bf(float f) {
    __hip_bfloat16 b = __float2bfloat16(f);   // RNE
    return *reinterpret_cast<unsigned short*>(&b);
}
__device__ __forceinline__ float bf2f(unsigned short u) {
    unsigned int x = ((unsigned int)u) << 16;
    return __uint_as_float(x);
}

// ---------------- prep: zero gbcur+sums, convert W1/W2 -> bf16 transposed ----------------
// Wt[n][k] = W[k][n]; B-fragment loads then read 16B contiguous per lane.

__global__ __launch_bounds__(256) void k_prep(int* __restrict__ gbcur, int nb,
                                              float* __restrict__ sums, int m,
                                              const float* __restrict__ W1,
                                              const float* __restrict__ W2,
                                              unsigned short* __restrict__ Wt1,
                                              unsigned short* __restrict__ Wt2) {
    int i = blockIdx.x * 256 + threadIdx.x;
    if (i < nb) gbcur[i] = 0;
    if (i < m) sums[i] = 0.f;
    if (i < HD * HD) {
        int k = i >> 7, nn = i & 127;
        Wt1[nn * HD + k] = f2bf(W1[i]);
        Wt2[nn * HD + k] = f2bf(W2[i]);
    }
}

// ---------------- CSR build via bucketed counting sort ----------------

__global__ __launch_bounds__(256) void k_bucket(const int* __restrict__ src,
                                                const int* __restrict__ dst, int E,
                                                int* __restrict__ gbcur,
                                                int* __restrict__ stage, int nb) {
    __shared__ int lh[256];
    __shared__ int gb[256];
    int t = threadIdx.x;
    if (t < nb) lh[t] = 0;
    __syncthreads();

    int e0 = blockIdx.x * 4096;
    int bk[16]; int lr[16]; int rec[16];
    #pragma unroll
    for (int j = 0; j < 16; ++j) {
        int e = e0 + j * 256 + t;
        if (e < E) {
            int d = dst[e];
            int s = src[e];
            bk[j]  = d >> 8;
            rec[j] = ((d & 255) << 16) | s;       // src < 65536
            lr[j]  = atomicAdd(&lh[bk[j]], 1);    // local rank
        } else {
            bk[j] = -1; lr[j] = 0; rec[j] = 0;
        }
    }
    __syncthreads();
    if (t < nb) gb[t] = atomicAdd(&gbcur[t], lh[t]);   // reserve run per bucket
    __syncthreads();
    #pragma unroll
    for (int j = 0; j < 16; ++j) {
        if (bk[j] >= 0) {
            int p = gb[bk[j]] + lr[j];
            if (p < BCAP) stage[bk[j] * BCAP + p] = rec[j];
        }
    }
}

// build: per-bucket local CSR; bucket bases via redundant in-block scan of gbcnt.

__global__ __launch_bounds__(256) void k_build(const int* __restrict__ stage,
                                               const int* __restrict__ gbcnt,
                                               int* __restrict__ col,
                                               int* __restrict__ row_start,
                                               float* __restrict__ dinv, int n, int nb) {
    __shared__ int rec_s[BCAP];
    __shared__ unsigned short rank_s[BCAP];
    __shared__ int hist[256];
    __shared__ int scan_s[256];
    int b = blockIdx.x, t = threadIdx.x;

    // redundant scan of bucket counts -> this bucket's base
    int cval = (t < nb) ? gbcnt[t] : 0;
    scan_s[t] = cval;
    __syncthreads();
    #pragma unroll
    for (int off = 1; off < 256; off <<= 1) {
        int v = (t >= off) ? scan_s[t - off] : 0;
        __syncthreads();
        scan_s[t] += v;
        __syncthreads();
    }
    __shared__ int base_s;
    if (t == b) base_s = scan_s[t] - cval;
    if (b == 0 && t == 0) row_start[n] = scan_s[nb - 1];
    __syncthreads();
    int base = base_s;
    int cnt  = min(gbcnt[b], BCAP);
    int node0 = b << 8;

    hist[t] = 0;
    __syncthreads();
    for (int e = t; e < cnt; e += 256) {
        int r = stage[b * BCAP + e];
        rec_s[e] = r;
        rank_s[e] = (unsigned short)atomicAdd(&hist[r >> 16], 1);
    }
    __syncthreads();

    int deg = hist[t];
    int node = node0 + t;
    if (node < n) dinv[node] = 1.0f / sqrtf((float)(deg + 1));  // +1 self loop

    scan_s[t] = deg;
    __syncthreads();
    #pragma unroll
    for (int off = 1; off < 256; off <<= 1) {
        int v = (t >= off) ? scan_s[t - off] : 0;
        __syncthreads();
        scan_s[t] += v;
        __syncthreads();
    }
    int lrs = scan_s[t] - deg;      // local exclusive prefix
    hist[t] = lrs;                  // reuse hist as lrs table
    if (node < n) row_start[node] = base + lrs;
    __syncthreads();

    for (int e = t; e < cnt; e += 256) {
        int r = rec_s[e];
        col[base + hist[r >> 16] + rank_s[e]] = r & 0xFFFF;
    }
}

// ---------------- MFMA GEMM: Y[n,128](bf16) = X[n,128](f32|bf16) @ Wt^T ----------------
// 4 waves/block, 16 rows/wave. A frags direct from global; B frags from bf16 Wt
// (L2-resident). mfma_f32_16x16x32_bf16: A[m][k]: m=lane&15, k=(lane>>4)*8+i;
// B[k][n]: n=lane&15, same k map; D: row=(lane>>4)*4+r, col=lane&15.

template <typename TIN>
__global__ __launch_bounds__(256) void k_gemm_mfma(const TIN* __restrict__ X,
                                                   const unsigned short* __restrict__ Wt,
                                                   unsigned short* __restrict__ Y, int n) {
    int wave = threadIdx.x >> 6, lane = threadIdx.x & 63;
    int lm = lane & 15, g = lane >> 4;
    int m0 = blockIdx.x * 64 + wave * 16;
    int row = m0 + lm;
    bool rok = row < n;

    f32x4 acc[8] = {};

    #pragma unroll
    for (int kb = 0; kb < 4; ++kb) {
        int k0 = kb * 32 + g * 8;
        bf16x8 a = {0, 0, 0, 0, 0, 0, 0, 0};
        if (rok) {
            if constexpr (sizeof(TIN) == 4) {
                const float* xp = (const float*)X + (size_t)row * HD + k0;
                float4 v0 = *(const float4*)xp;
                float4 v1 = *(const float4*)(xp + 4);
                a[0] = (short)f2bf(v0.x); a[1] = (short)f2bf(v0.y);
                a[2] = (short)f2bf(v0.z); a[3] = (short)f2bf(v0.w);
                a[4] = (short)f2bf(v1.x); a[5] = (short)f2bf(v1.y);
                a[6] = (short)f2bf(v1.z); a[7] = (short)f2bf(v1.w);
            } else {
                a = *(const bf16x8*)((const unsigned short*)X + (size_t)row * HD + k0);
            }
        }
        #pragma unroll
        for (int nt = 0; nt < 8; ++nt) {
            int ncol = nt * 16 + lm;
            bf16x8 bfrag = *(const bf16x8*)(Wt + (size_t)ncol * HD + k0);
            acc[nt] = __builtin_amdgcn_mfma_f32_16x16x32_bf16(a, bfrag, acc[nt], 0, 0, 0);
        }
    }

    #pragma unroll
    for (int nt = 0; nt < 8; ++nt) {
        #pragma unroll
        for (int r = 0; r < 4; ++r) {
            int orow = m0 + g * 4 + r;
            if (orow < n) Y[(size_t)orow * HD + nt * 16 + lm] = f2bf(acc[nt][r]);
        }
    }
}

// ---------------- Aggregation (bf16 gather, f32 accumulate, bf16 out) ----------------
// out[v] = relu( sum_{s} h[s]*dinv[s]*dinv[v] + h[v]*dinv[v]^2 + bias ).
// col[e] / dinv[s] loads are wave-uniform (broadcast); h row gathers are 256B/wave.

__global__ __launch_bounds__(256) void k_agg(const unsigned short* __restrict__ hin,
                                             const float* __restrict__ dinv,
                                             const int* __restrict__ row_start,
                                             const int* __restrict__ col,
                                             const float* __restrict__ bias,
                                             unsigned short* __restrict__ hout, int n) {
    int wave = threadIdx.x >> 6;
    int lane = threadIdx.x & 63;
    int v = blockIdx.x * 4 + wave;
    if (v >= n) return;

    float dv = dinv[v];
    int f = lane * 2;
    ushort2 sv = *(const ushort2*)(hin + (size_t)v * HD + f);
    float selfw = dv * dv;
    float accx = bf2f(sv.x) * selfw;
    float accy = bf2f(sv.y) * selfw;

    int e  = row_start[v];
    int e1 = row_start[v + 1];

    for (; e + 8 <= e1; e += 8) {
        int s0 = col[e],   s1 = col[e+1], s2 = col[e+2], s3 = col[e+3];
        int s4 = col[e+4], s5 = col[e+5], s6 = col[e+6], s7 = col[e+7];
        float w0 = dinv[s0]*dv, w1 = dinv[s1]*dv, w2 = dinv[s2]*dv, w3 = dinv[s3]*dv;
        float w4 = dinv[s4]*dv, w5 = dinv[s5]*dv, w6 = dinv[s6]*dv, w7 = dinv[s7]*dv;
        ushort2 a0 = *(const ushort2*)(hin + (size_t)s0 * HD + f);
        ushort2 a1 = *(const ushort2*)(hin + (size_t)s1 * HD + f);
        ushort2 a2 = *(const ushort2*)(hin + (size_t)s2 * HD + f);
        ushort2 a3 = *(const ushort2*)(hin + (size_t)s3 * HD + f);
        ushort2 a4 = *(const ushort2*)(hin + (size_t)s4 * HD + f);
        ushort2 a5 = *(const ushort2*)(hin + (size_t)s5 * HD + f);
        ushort2 a6 = *(const ushort2*)(hin + (size_t)s6 * HD + f);
        ushort2 a7 = *(const ushort2*)(hin + (size_t)s7 * HD + f);
        accx = fmaf(bf2f(a0.x), w0, accx); accy = fmaf(bf2f(a0.y), w0, accy);
        accx = fmaf(bf2f(a1.x), w1, accx); accy = fmaf(bf2f(a1.y), w1, accy);
        accx = fmaf(bf2f(a2.x), w2, accx); accy = fmaf(bf2f(a2.y), w2, accy);
        accx = fmaf(bf2f(a3.x), w3, accx); accy = fmaf(bf2f(a3.y), w3, accy);
        accx = fmaf(bf2f(a4.x), w4, accx); accy = fmaf(bf2f(a4.y), w4, accy);
        accx = fmaf(bf2f(a5.x), w5, accx); accy = fmaf(bf2f(a5.y), w5, accy);
        accx = fmaf(bf2f(a6.x), w6, accx); accy = fmaf(bf2f(a6.y), w6, accy);
        accx = fmaf(bf2f(a7.x), w7, accx); accy = fmaf(bf2f(a7.y), w7, accy);
    }

    {   // predicated tail
        int rem = e1 - e;
        int sx[7]; ushort2 a[7];
        #pragma unroll
        for (int j = 0; j < 7; ++j) {
            if (j < rem) {
                sx[j] = col[e + j];
                a[j] = *(const ushort2*)(hin + (size_t)sx[j] * HD + f);
            }
        }
        #pragma unroll
        for (int j = 0; j < 7; ++j) {
            if (j < rem) {
                float w = dinv[sx[j]] * dv;
                accx = fmaf(bf2f(a[j].x), w, accx);
                accy = fmaf(bf2f(a[j].y), w, accy);
            }
        }
    }

    float2 b = *(const float2*)(bias + f);
    ushort2 o;
    o.x = f2bf(fmaxf(accx + b.x, 0.f));
    o.y = f2bf(fmaxf(accy + b.y, 0.f));
    *(ushort2*)(hout + (size_t)v * HD + f) = o;
}

// ---------------- Mean-pool stage 1: per-chunk segmented partial sums (bf16 in) --------

#define POOL_ROWS 32

__global__ __launch_bounds__(128) void k_pool_partial(const unsigned short* __restrict__ h,
                                                      const int* __restrict__ batch,
                                                      float* __restrict__ sums, int n) {
    __shared__ int bs[POOL_ROWS];
    int t = threadIdx.x;
    int r0 = blockIdx.x * POOL_ROWS;
    int r1 = min(r0 + POOL_ROWS, n);
    int cnt = r1 - r0;
    if (t < cnt) bs[t] = batch[r0 + t];
    __syncthreads();

    int g = bs[0];
    float acc = 0.f;
    for (int i = 0; i < cnt; ++i) {
        int bg = bs[i];
        if (bg != g) {
            atomicAdd(&sums[(size_t)g * HD + t], acc);
            acc = 0.f;
            g = bg;
        }
        acc += bf2f(h[(size_t)(r0 + i) * HD + t]);
    }
    atomicAdd(&sums[(size_t)g * HD + t], acc);
}

// ---------------- mean + FC ----------------

__global__ __launch_bounds__(128) void k_fc(const float* __restrict__ sums,
                                            const int* __restrict__ batch,
                                            const float* __restrict__ Wfc,
                                            const float* __restrict__ bfc,
                                            float* __restrict__ out, int n) {
    int g = blockIdx.x;
    int t = threadIdx.x;
    __shared__ int slo, shi;
    if (t == 0) {
        int lo = 0, hi = n;
        while (lo < hi) { int m = (lo + hi) >> 1; if (batch[m] < g) lo = m + 1; else hi = m; }
        slo = lo;
        lo = 0; hi = n;
        while (lo < hi) { int m = (lo + hi) >> 1; if (batch[m] < g + 1) lo = m + 1; else hi = m; }
        shi = lo;
    }
    __syncthreads();
    float cnt = (float)(shi - slo);
    __shared__ float sp[HD];
    sp[t] = sums[(size_t)g * HD + t] / fmaxf(cnt, 1.f);
    __syncthreads();
    if (t < NL) {
        float o = bfc[t];
        for (int k = 0; k < HD; ++k) o = fmaf(sp[k], Wfc[k * NL + t], o);
        out[g * NL + t] = o;
    }
}

// ---------------- launch ----------------

extern "C" void kernel_launch(void* const* d_in, const int* in_sizes, int n_in,
                              void* d_out, int out_size, void* d_ws, size_t ws_size,
                              hipStream_t stream) {
    const float* x    = (const float*)d_in[0];
    const int*   ei   = (const int*)d_in[1];
    const int*   batch= (const int*)d_in[2];
    const float* W1   = (const float*)d_in[3];
    const float* b1   = (const float*)d_in[4];
    const float* W2   = (const float*)d_in[5];
    const float* b2   = (const float*)d_in[6];
    const float* Wfc  = (const float*)d_in[7];
    const float* bfc  = (const float*)d_in[8];
    float* out = (float*)d_out;

    int n = in_sizes[0] / HD;       // 50000
    int E = in_sizes[1] / 2;        // 800000
    int G = out_size / NL;          // 128
    const int* srcp = ei;
    const int* dstp = ei + E;

    int nb = (n + 255) >> 8;        // 196 buckets of 256 dst nodes

    char* ws = (char*)d_ws;
    auto align256 = [](size_t v) { return (v + 255) & ~(size_t)255; };
    size_t o = 0;
    int*   row_start = (int*)(ws + o); o = align256(o + (size_t)(n + 1) * 4);
    int*   gbcur     = (int*)(ws + o); o = align256(o + (size_t)nb * 4);
    float* dinv      = (float*)(ws + o); o = align256(o + (size_t)n * 4);
    int*   col       = (int*)(ws + o); o = align256(o + (size_t)E * 4);
    unsigned short* tmp  = (unsigned short*)(ws + o); o = align256(o + (size_t)n * HD * 2);
    unsigned short* tmp2 = (unsigned short*)(ws + o); o = align256(o + (size_t)n * HD * 2);
    int*   stage     = (int*)(ws + o); o = align256(o + (size_t)nb * BCAP * 4);
    float* sums      = (float*)(ws + o); o = align256(o + (size_t)G * HD * 4);
    unsigned short* Wt1 = (unsigned short*)(ws + o); o = align256(o + (size_t)HD * HD * 2);
    unsigned short* Wt2 = (unsigned short*)(ws + o); o = align256(o + (size_t)HD * HD * 2);

    int mZero = G * HD;             // 16384 floats of sums
    k_prep<<<(HD * HD + 255) / 256, 256, 0, stream>>>(gbcur, nb, sums, mZero,
                                                      W1, W2, Wt1, Wt2);

    int nblkC = (E + 4095) / 4096;  // 196
    k_bucket<<<nblkC, 256, 0, stream>>>(srcp, dstp, E, gbcur, stage, nb);
    k_build <<<nb, 256, 0, stream>>>(stage, gbcur, col, row_start, dinv, n, nb);

    k_gemm_mfma<float><<<(n + 63) / 64, 256, 0, stream>>>(x, Wt1, tmp, n);
    k_agg<<<(n + 3) / 4, 256, 0, stream>>>(tmp, dinv, row_start, col, b1, tmp2, n);
    k_gemm_mfma<unsigned short><<<(n + 63) / 64, 256, 0, stream>>>(tmp2, Wt2, tmp, n);
    k_agg<<<(n + 3) / 4, 256, 0, stream>>>(tmp, dinv, row_start, col, b2, tmp2, n);

    k_pool_partial<<<(n + POOL_ROWS - 1) / POOL_ROWS, 128, 0, stream>>>(tmp2, batch, sums, n);
    k_fc<<<G, 128, 0, stream>>>(sums, batch, Wfc, bfc, out, n);
}